// Round 9
// baseline (260.984 us; speedup 1.0000x reference)
//
#include <hip/hip_runtime.h>

#define B_ 8
#define N_ 262144
#define M_ 100
#define C_ 7
#define EPSF 1e-7f
#define AB_ 2048                 // anchors per k_main block
#define CH_ (N_ / AB_)           // 128 chunks
// fallback path (R6-proven) params
#define SEG_ 4
#define SEGN_ (N_ / SEG_)

typedef unsigned long long ull;
typedef float v2f __attribute__((ext_vector_type(2)));

__device__ __forceinline__ float softplus0(float x) {
  // jnp.logaddexp(0, x) = max(x,0) + log1p(exp(-|x|))
  return fmaxf(x, 0.0f) + log1pf(expf(-fabsf(x)));
}

__device__ __forceinline__ ull u64min(ull a, ull b) { return b < a ? b : a; }

// ---------------- k_main: softplus + neg-weight + per-chunk argmin partials ----------------
// grid (CH_, B), 256 threads. Packed-f32 (v_pk_*) d2 core: anchors processed as
// 4 pairs {2q, 2q+1}; per-m argmin via scalar k-ascending strict-< scan (exact
// lowest-n tie-break), ONE u64 pack, 3-step bpermute butterfly, LDS combine.
// No atomics at all: sp/sw block sums stored per-chunk (f32), reduced later.
__global__ void __launch_bounds__(256)
k_main(const float* __restrict__ pred_cls,
       const float* __restrict__ anchors,
       const float* __restrict__ gt_boxes,
       float* __restrict__ sp_part,
       float* __restrict__ sw_part,
       ull* __restrict__ part) {
  const int b = blockIdx.y;
  const int c = blockIdx.x;   // anchor chunk (AB_ anchors)
  const int t = threadIdx.x;  // 256

  __shared__ float4 gt4[M_];   // (gx, gy, gx^2+gy^2, -)
  __shared__ float red[256];
  __shared__ ull wb[M_][33];   // per-8-lane best per m (+1 pad vs bank conflicts)

  if (t < M_) {
    float4 g = reinterpret_cast<const float4*>(gt_boxes)[b * M_ + t];
    float gx = __fmul_rn(__fadd_rn(g.x, g.z), 0.5f);
    float gy = __fmul_rn(__fadd_rn(g.y, g.w), 0.5f);
    gt4[t] = make_float4(gx, gy, __fadd_rn(__fmul_rn(gx, gx), __fmul_rn(gy, gy)), 0.f);
  }

  // ---- phase 1: softplus over this block's slice (AB_*C_ = 14336 floats),
  // fully retired before anchor state goes live (R5 lesson: no spill).
  const float4* pc = reinterpret_cast<const float4*>(
      pred_cls + (size_t)b * (size_t)(N_ * C_) + (size_t)c * (AB_ * C_));
  float acc_sp = 0.f;
  for (int k = 0; k < 14; ++k) {
    float4 v = pc[t + k * 256];
    acc_sp += softplus0(v.x) + softplus0(v.y) + softplus0(v.z) + softplus0(v.w);
  }
  red[t] = acc_sp;
  __syncthreads();
  for (int s = 128; s > 0; s >>= 1) {
    if (t < s) red[t] += red[t + s];
    __syncthreads();
  }
  if (t == 0) sp_part[b * CH_ + c] = red[0];

  // ---- phase 2: 8 anchors/thread as 4 packed pairs {2q, 2q+1}.
  const int n0 = c * AB_;
  const float2* an = reinterpret_cast<const float2*>(anchors);
  v2f ax2[4], ay2[4], t22[4], mind2[4];
#pragma unroll
  for (int q = 0; q < 4; ++q) {
    float2 a0 = an[n0 + t + (2 * q) * 256];
    float2 a1 = an[n0 + t + (2 * q + 1) * 256];
    ax2[q] = (v2f){a0.x, a1.x};
    ay2[q] = (v2f){a0.y, a1.y};
    // t2 with scalar _rn ops (blocks any mul+add contraction; bit-exact vs R0)
    t22[q] = (v2f){__fadd_rn(__fmul_rn(a0.x, a0.x), __fmul_rn(a0.y, a0.y)),
                   __fadd_rn(__fmul_rn(a1.x, a1.x), __fmul_rn(a1.y, a1.y))};
    mind2[q] = (v2f){__int_as_float(0x7f800000), __int_as_float(0x7f800000)};
  }
  const int lane = t & 63;
  int bidx[3];
#pragma unroll
  for (int i = 0; i < 3; ++i) bidx[i] = ((lane ^ (1 << i)) << 2);  // byte idx, hoisted
  __syncthreads();  // gt4 ready

  const v2f zero2 = (v2f){0.f, 0.f};
#pragma unroll 2
  for (int m = 0; m < M_; ++m) {
    const float4 g = gt4[m];
    const v2f gx2 = (v2f){g.x, g.x};
    const v2f gy2 = (v2f){g.y, g.y};
    const v2f gz2 = (v2f){g.z, g.z};
    float bd = __int_as_float(0x7f800000);
    int bk = 0;
#pragma unroll
    for (int q = 0; q < 4; ++q) {
      v2f gmul = gx2 * ax2[q];                                   // pk_mul
      v2f dot  = __builtin_elementwise_fma(gy2, ay2[q], gmul);   // pk_fma
      v2f d2   = (gz2 + t22[q]) - (dot + dot);                   // adds/sub of non-mul
      d2 = __builtin_elementwise_max(d2, zero2);                 // ref: clip(d2,0)
      mind2[q] = __builtin_elementwise_min(mind2[q], d2);
      // scan in k-ascending order (k=2q then 2q+1): strict < keeps lowest n
      if (d2.x < bd) { bd = d2.x; bk = 2 * q; }
      if (d2.y < bd) { bd = d2.y; bk = 2 * q + 1; }
    }
    ull pk = ((ull)__float_as_uint(bd) << 32) |
             (ull)(unsigned)(n0 + t + (bk << 8));
    // 3-step butterfly: per-8-lane (d2, n) min
#pragma unroll
    for (int i = 0; i < 3; ++i) {
      int lo = __builtin_amdgcn_ds_bpermute(bidx[i], (int)(unsigned)(pk & 0xffffffffULL));
      int hi = __builtin_amdgcn_ds_bpermute(bidx[i], (int)(unsigned)(pk >> 32));
      ull o = ((ull)(unsigned)hi << 32) | (ull)(unsigned)lo;
      pk = u64min(pk, o);
    }
    if ((t & 7) == 0) wb[m][t >> 3] = pk;
  }
  __syncthreads();

  // neg-weight partial sum (k order 0..7 preserved: .x then .y per pair)
  float accw = 0.f;
#pragma unroll
  for (int q = 0; q < 4; ++q) {
    accw += (sqrtf(mind2[q].x) > 3.0f) ? 1.0f : 0.1f;
    accw += (sqrtf(mind2[q].y) > 3.0f) ? 1.0f : 0.1f;
  }
  red[t] = accw;
  __syncthreads();
  for (int s = 128; s > 0; s >>= 1) {
    if (t < s) red[t] += red[t + s];
    __syncthreads();
  }
  if (t == 0) sw_part[b * CH_ + c] = red[0];

  // block combine: 32 per-8-lane bests -> one plain store per (b, m, chunk)
  if (t < M_) {
    const ull* w = wb[t];
    ull v0 = w[0], v1 = w[1], v2 = w[2], v3 = w[3];
    for (int j = 4; j < 32; j += 4) {
      v0 = u64min(v0, w[j]);
      v1 = u64min(v1, w[j + 1]);
      v2 = u64min(v2, w[j + 2]);
      v3 = u64min(v3, w[j + 3]);
    }
    part[((size_t)(b * M_ + t)) * CH_ + c] = u64min(u64min(v0, v1), u64min(v2, v3));
  }
}

// ---------------- k_finalall: everything else in ONE kernel (1 block, 1024 thr) ----------------
// Sub-block b = t>>7 (128 threads) handles image b: chunk-partial argmin reduce,
// sp/sw f64 sums, dedup/uniqueness, sorted-vs-matched GIoU, then thread 0 combines.
__global__ void __launch_bounds__(1024)
k_finalall(const float* __restrict__ pred_cls,
           const float* __restrict__ pred_reg,
           const float* __restrict__ anchors,
           const float* __restrict__ strides,
           const float* __restrict__ gt_boxes,
           const int* __restrict__ gt_labels,
           const ull* __restrict__ part,
           const float* __restrict__ sp_part,
           const float* __restrict__ sw_part,
           float* __restrict__ out) {
  const int t  = threadIdx.x;
  const int b  = t >> 7;
  const int tt = t & 127;
  __shared__ float4 gt4[B_][M_];
  __shared__ unsigned asg[B_][M_];
  __shared__ int cid[B_][M_];
  __shared__ unsigned srt[B_][M_];
  __shared__ float red[B_][128];
  __shared__ double redd[B_][128];
  __shared__ int dup[B_];
  __shared__ float tgtT[B_], corrT[B_], lcs[B_], lbs[B_];
  __shared__ double spT[B_], swT[B_];

  if (tt == 0) dup[b] = 0;
  if (tt < M_) {
    const ull* p = part + ((size_t)(b * M_ + tt)) * CH_;
    ull v0 = p[0], v1 = p[1], v2 = p[2], v3 = p[3];
    for (int c = 4; c < CH_; c += 4) {
      v0 = u64min(v0, p[c]);
      v1 = u64min(v1, p[c + 1]);
      v2 = u64min(v2, p[c + 2]);
      v3 = u64min(v3, p[c + 3]);
    }
    asg[b][tt] = (unsigned)(u64min(u64min(v0, v1), u64min(v2, v3)) & 0xffffffffULL);
    int cc = gt_labels[b * M_ + tt] - 1;
    cc = cc < 0 ? 0 : (cc > C_ - 1 ? C_ - 1 : cc);
    cid[b][tt] = cc;
    float4 g = reinterpret_cast<const float4*>(gt_boxes)[b * M_ + tt];
    float gx = __fmul_rn(__fadd_rn(g.x, g.z), 0.5f);
    float gy = __fmul_rn(__fadd_rn(g.y, g.w), 0.5f);
    gt4[b][tt] = make_float4(gx, gy, __fadd_rn(__fmul_rn(gx, gx), __fmul_rn(gy, gy)), 0.f);
  }

  // sp / sw f64 reductions over the 128 chunk partials
  redd[b][tt] = (double)sp_part[b * CH_ + tt];
  __syncthreads();
  for (int s = 64; s > 0; s >>= 1) {
    if (tt < s) redd[b][tt] += redd[b][tt + s];
    __syncthreads();
  }
  if (tt == 0) spT[b] = redd[b][0];
  __syncthreads();
  redd[b][tt] = (double)sw_part[b * CH_ + tt];
  __syncthreads();
  for (int s = 64; s > 0; s >>= 1) {
    if (tt < s) redd[b][tt] += redd[b][tt + s];
    __syncthreads();
  }
  if (tt == 0) swT[b] = redd[b][0];
  __syncthreads();

  // tgt sum with (anchor,cls)-pair dedup; anchor-dup detection for uniqueness;
  // pos-correction: for each DISTINCT assigned anchor add its neg-weight.
  float tg = 0.f, corr = 0.f;
  if (tt < M_) {
    bool dupPair = false, dupIdx = false;
    for (int m = 0; m < tt; ++m) {
      if (asg[b][m] == asg[b][tt]) {
        dupIdx = true;
        if (cid[b][m] == cid[b][tt]) dupPair = true;
      }
    }
    if (!dupPair) tg = pred_cls[((size_t)b * N_ + asg[b][tt]) * C_ + cid[b][tt]];
    if (dupIdx) atomicAdd(&dup[b], 1);
    if (!dupIdx) {
      float2 a = reinterpret_cast<const float2*>(anchors)[asg[b][tt]];
      float t2 = __fadd_rn(__fmul_rn(a.x, a.x), __fmul_rn(a.y, a.y));
      float mind = __int_as_float(0x7f800000);
      for (int m = 0; m < M_; ++m) {
        float4 g = gt4[b][m];
        float dot = __fmaf_rn(g.y, a.y, __fmul_rn(g.x, a.x));
        float d2  = __fsub_rn(__fadd_rn(g.z, t2), __fadd_rn(dot, dot));
        mind = fminf(mind, fmaxf(d2, 0.0f));
      }
      corr = (sqrtf(mind) > 3.0f) ? 1.0f : 0.1f;
    }
  }
  red[b][tt] = tg;
  __syncthreads();
  for (int s = 64; s > 0; s >>= 1) {
    if (tt < s) red[b][tt] += red[b][tt + s];
    __syncthreads();
  }
  if (tt == 0) tgtT[b] = red[b][0];
  __syncthreads();
  red[b][tt] = corr;
  __syncthreads();
  for (int s = 64; s > 0; s >>= 1) {
    if (tt < s) red[b][tt] += red[b][tt + s];
    __syncthreads();
  }
  if (tt == 0) corrT[b] = red[b][0];
  __syncthreads();
  const bool uniqueAll = (dup[b] == 0);

  if (uniqueAll && tt < M_) {
    const unsigned v = asg[b][tt];
    int rank = 0;
    for (int m = 0; m < M_; ++m) rank += (asg[b][m] < v) ? 1 : 0;
    srt[b][rank] = v;
  }
  __syncthreads();

  float gl = 0.f;
  if (tt < M_) {
    const unsigned q = uniqueAll ? srt[b][tt] : asg[b][tt];
    float4 r = reinterpret_cast<const float4*>(pred_reg)[(size_t)b * N_ + q];
    float2 a = reinterpret_cast<const float2*>(anchors)[q];
    float s = strides[q];
    float cx = a.x + r.x * s, cy = a.y + r.y * s;
    float hx = (expf(r.z) * s) * 0.5f, hy = (expf(r.w) * s) * 0.5f;
    float px0 = cx - hx, py0 = cy - hy, px1 = cx + hx, py1 = cy + hy;
    float4 g = reinterpret_cast<const float4*>(gt_boxes)[b * M_ + tt];
    float ap = (px1 - px0) * (py1 - py0);
    float ag = (g.z - g.x) * (g.w - g.y);
    float ltx = fmaxf(px0, g.x), lty = fmaxf(py0, g.y);
    float rbx = fminf(px1, g.z), rby = fminf(py1, g.w);
    float wix = fmaxf(rbx - ltx, 0.f), wiy = fmaxf(rby - lty, 0.f);
    float inter = wix * wiy;
    float uni = ap + ag - inter;
    float iou = inter / (uni + EPSF);
    float lcx = fminf(px0, g.x), lcy = fminf(py0, g.y);
    float rcx = fmaxf(px1, g.z), rcy = fmaxf(py1, g.w);
    float wcx = fmaxf(rcx - lcx, 0.f), wcy = fmaxf(rcy - lcy, 0.f);
    float ac = wcx * wcy;
    float giou = iou - (ac - uni) / (ac + EPSF);
    gl = 1.f - giou;
  }
  __syncthreads();
  red[b][tt] = gl;
  __syncthreads();
  for (int s = 64; s > 0; s >>= 1) {
    if (tt < s) red[b][tt] += red[b][tt + s];
    __syncthreads();
  }
  if (tt == 0) {
    lbs[b] = red[b][0] / (float)M_;
    float bce = (float)((spT[b] - (double)tgtT[b]) / (double)(N_ * C_));
    float swm = (float)((swT[b] + (double)corrT[b]) / (double)N_);
    lcs[b] = bce * swm;
  }
  __syncthreads();
  if (t == 0) {
    float sc = 0.f, sb = 0.f;
    for (int i = 0; i < B_; ++i) { sc += lcs[i]; sb += lbs[i]; }
    out[0] = sc / 8.0f + 2.0f * (sb / 8.0f);
  }
}

// ---------------- fallback (R6-proven) kernels, used if ws_size is small ----------------
__global__ void __launch_bounds__(256)
k_passA(const float* __restrict__ pred_cls,
        const float* __restrict__ anchors,
        const float* __restrict__ gt_boxes,
        double* __restrict__ sp_sum,
        double* __restrict__ swb_sum) {
  const int b = blockIdx.y;
  const int c = blockIdx.x;
  const int t = threadIdx.x;
  __shared__ float4 gt4[M_];
  __shared__ float red[256];
  if (t < M_) {
    float4 g = reinterpret_cast<const float4*>(gt_boxes)[b * M_ + t];
    float gx = __fmul_rn(__fadd_rn(g.x, g.z), 0.5f);
    float gy = __fmul_rn(__fadd_rn(g.y, g.w), 0.5f);
    gt4[t] = make_float4(gx, gy, __fadd_rn(__fmul_rn(gx, gx), __fmul_rn(gy, gy)), 0.f);
  }
  const float4* pc = reinterpret_cast<const float4*>(
      pred_cls + (size_t)b * (size_t)(N_ * C_) + (size_t)c * (1024 * C_));
  float acc_sp = 0.f;
#pragma unroll
  for (int k = 0; k < 7; ++k) {
    float4 v = pc[t + k * 256];
    acc_sp += softplus0(v.x) + softplus0(v.y) + softplus0(v.z) + softplus0(v.w);
  }
  red[t] = acc_sp;
  __syncthreads();
  for (int s = 128; s > 0; s >>= 1) {
    if (t < s) red[t] += red[t + s];
    __syncthreads();
  }
  if (t == 0) atomicAdd(&sp_sum[b], (double)red[0]);
  const int n0 = c * 1024;
  float ax[4], ay[4], t2[4], mind[4];
#pragma unroll
  for (int k = 0; k < 4; ++k) {
    float2 a = reinterpret_cast<const float2*>(anchors)[n0 + t + k * 256];
    ax[k] = a.x; ay[k] = a.y;
    t2[k] = __fadd_rn(__fmul_rn(a.x, a.x), __fmul_rn(a.y, a.y));
    mind[k] = __int_as_float(0x7f800000);
  }
#pragma unroll 2
  for (int m = 0; m < M_; ++m) {
    const float4 g = gt4[m];
#pragma unroll
    for (int k = 0; k < 4; ++k) {
      float dot = __fmaf_rn(g.y, ay[k], __fmul_rn(g.x, ax[k]));
      float d2  = __fsub_rn(__fadd_rn(g.z, t2[k]), __fadd_rn(dot, dot));
      mind[k] = fminf(mind[k], fmaxf(d2, 0.0f));
    }
  }
  float accw = 0.f;
#pragma unroll
  for (int k = 0; k < 4; ++k) accw += (sqrtf(mind[k]) > 3.0f) ? 1.0f : 0.1f;
  __syncthreads();
  red[t] = accw;
  __syncthreads();
  for (int s = 128; s > 0; s >>= 1) {
    if (t < s) red[t] += red[t + s];
    __syncthreads();
  }
  if (t == 0) atomicAdd(&swb_sum[b], (double)red[0]);
}

__global__ void __launch_bounds__(256)
k_argmin(const float* __restrict__ anchors,
         const float* __restrict__ gt_boxes,
         ull* __restrict__ amin) {
  const int bm  = blockIdx.y;
  const int seg = blockIdx.x;
  const float4 g = reinterpret_cast<const float4*>(gt_boxes)[bm];
  const float gx = __fmul_rn(__fadd_rn(g.x, g.z), 0.5f);
  const float gy = __fmul_rn(__fadd_rn(g.y, g.w), 0.5f);
  const float t1 = __fadd_rn(__fmul_rn(gx, gx), __fmul_rn(gy, gy));
  const float2* an = reinterpret_cast<const float2*>(anchors);
  float best = __int_as_float(0x7f800000);
  unsigned bestn = 0;
  const int n0 = seg * SEGN_;
#pragma unroll 4
  for (int n = n0 + threadIdx.x; n < n0 + SEGN_; n += 256) {
    float2 a = an[n];
    float t2  = __fadd_rn(__fmul_rn(a.x, a.x), __fmul_rn(a.y, a.y));
    float dot = __fmaf_rn(gy, a.y, __fmul_rn(gx, a.x));
    float d2  = __fsub_rn(__fadd_rn(t1, t2), __fadd_rn(dot, dot));
    d2 = fmaxf(d2, 0.0f);
    if (d2 < best) { best = d2; bestn = (unsigned)n; }
  }
  ull pk = ((ull)__float_as_uint(best) << 32) | (ull)bestn;
  __shared__ ull red[256];
  const int t = threadIdx.x;
  red[t] = pk;
  __syncthreads();
  for (int s = 128; s > 0; s >>= 1) {
    if (t < s) {
      ull o = red[t + s];
      if (o < red[t]) red[t] = o;
    }
    __syncthreads();
  }
  if (t == 0) atomicMin(&amin[bm], red[0]);
}

__global__ void __launch_bounds__(128)
k_final_img(const float* __restrict__ pred_cls,
            const float* __restrict__ pred_reg,
            const float* __restrict__ anchors,
            const float* __restrict__ strides,
            const float* __restrict__ gt_boxes,
            const int* __restrict__ gt_labels,
            const ull* __restrict__ amin,
            const double* __restrict__ sp_sum,
            const double* __restrict__ swb_sum,
            float* __restrict__ lc, float* __restrict__ lb) {
  const int b = blockIdx.x;
  const int t = threadIdx.x;  // 128
  __shared__ unsigned asg[M_];
  __shared__ int cid[M_];
  __shared__ unsigned srt[M_];
  __shared__ float4 gt4[M_];
  __shared__ float red[128];
  __shared__ int dupCount;
  if (t == 0) dupCount = 0;
  if (t < M_) {
    asg[t] = (unsigned)(amin[b * M_ + t] & 0xffffffffULL);
    int c = gt_labels[b * M_ + t] - 1;
    c = c < 0 ? 0 : (c > C_ - 1 ? C_ - 1 : c);
    cid[t] = c;
    float4 g = reinterpret_cast<const float4*>(gt_boxes)[b * M_ + t];
    float gx = __fmul_rn(__fadd_rn(g.x, g.z), 0.5f);
    float gy = __fmul_rn(__fadd_rn(g.y, g.w), 0.5f);
    gt4[t] = make_float4(gx, gy, __fadd_rn(__fmul_rn(gx, gx), __fmul_rn(gy, gy)), 0.f);
  }
  __syncthreads();

  float tg = 0.f, corr = 0.f;
  if (t < M_) {
    bool dupPair = false, dupIdx = false;
    for (int m = 0; m < t; ++m) {
      if (asg[m] == asg[t]) {
        dupIdx = true;
        if (cid[m] == cid[t]) dupPair = true;
      }
    }
    if (!dupPair) tg = pred_cls[((size_t)b * N_ + asg[t]) * C_ + cid[t]];
    if (dupIdx) atomicAdd(&dupCount, 1);
    if (!dupIdx) {
      float2 a = reinterpret_cast<const float2*>(anchors)[asg[t]];
      float t2 = __fadd_rn(__fmul_rn(a.x, a.x), __fmul_rn(a.y, a.y));
      float mind = __int_as_float(0x7f800000);
      for (int m = 0; m < M_; ++m) {
        float4 g = gt4[m];
        float dot = __fmaf_rn(g.y, a.y, __fmul_rn(g.x, a.x));
        float d2  = __fsub_rn(__fadd_rn(g.z, t2), __fadd_rn(dot, dot));
        mind = fminf(mind, fmaxf(d2, 0.0f));
      }
      corr = (sqrtf(mind) > 3.0f) ? 1.0f : 0.1f;
    }
  }
  red[t] = tg;
  __syncthreads();
  for (int s = 64; s > 0; s >>= 1) {
    if (t < s) red[t] += red[t + s];
    __syncthreads();
  }
  const float tgt_total = red[0];
  __syncthreads();
  red[t] = corr;
  __syncthreads();
  for (int s = 64; s > 0; s >>= 1) {
    if (t < s) red[t] += red[t + s];
    __syncthreads();
  }
  const float corr_total = red[0];
  const bool uniqueAll = (dupCount == 0);
  __syncthreads();

  if (uniqueAll && t < M_) {
    const unsigned v = asg[t];
    int rank = 0;
    for (int m = 0; m < M_; ++m) rank += (asg[m] < v) ? 1 : 0;
    srt[rank] = v;
  }
  __syncthreads();

  float gl = 0.f;
  if (t < M_) {
    const unsigned q = uniqueAll ? srt[t] : asg[t];
    float4 r = reinterpret_cast<const float4*>(pred_reg)[(size_t)b * N_ + q];
    float2 a = reinterpret_cast<const float2*>(anchors)[q];
    float s = strides[q];
    float cx = a.x + r.x * s, cy = a.y + r.y * s;
    float hx = (expf(r.z) * s) * 0.5f, hy = (expf(r.w) * s) * 0.5f;
    float px0 = cx - hx, py0 = cy - hy, px1 = cx + hx, py1 = cy + hy;
    float4 g = reinterpret_cast<const float4*>(gt_boxes)[b * M_ + t];
    float ap = (px1 - px0) * (py1 - py0);
    float ag = (g.z - g.x) * (g.w - g.y);
    float ltx = fmaxf(px0, g.x), lty = fmaxf(py0, g.y);
    float rbx = fminf(px1, g.z), rby = fminf(py1, g.w);
    float wix = fmaxf(rbx - ltx, 0.f), wiy = fmaxf(rby - lty, 0.f);
    float inter = wix * wiy;
    float uni = ap + ag - inter;
    float iou = inter / (uni + EPSF);
    float lcx = fminf(px0, g.x), lcy = fminf(py0, g.y);
    float rcx = fmaxf(px1, g.z), rcy = fmaxf(py1, g.w);
    float wcx = fmaxf(rcx - lcx, 0.f), wcy = fmaxf(rcy - lcy, 0.f);
    float ac = wcx * wcy;
    float giou = iou - (ac - uni) / (ac + EPSF);
    gl = 1.f - giou;
  }
  __syncthreads();
  red[t] = gl;
  __syncthreads();
  for (int s = 64; s > 0; s >>= 1) {
    if (t < s) red[t] += red[t + s];
    __syncthreads();
  }
  if (t == 0) {
    lb[b] = red[0] / (float)M_;
    float bce = (float)((sp_sum[b] - (double)tgt_total) / (double)(N_ * C_));
    float swm = (float)((swb_sum[b] + (double)corr_total) / (double)N_);
    lc[b] = bce * swm;
  }
}

__global__ void __launch_bounds__(64)
k_total(const float* __restrict__ lc, const float* __restrict__ lb,
        float* __restrict__ out) {
  if (threadIdx.x == 0 && blockIdx.x == 0) {
    float sc = 0.f, sb = 0.f;
    for (int b = 0; b < B_; ++b) { sc += lc[b]; sb += lb[b]; }
    out[0] = sc / 8.0f + 2.0f * (sb / 8.0f);
  }
}

// ---------------- launch ----------------
extern "C" void kernel_launch(void* const* d_in, const int* in_sizes, int n_in,
                              void* d_out, int out_size, void* d_ws, size_t ws_size,
                              hipStream_t stream) {
  (void)in_sizes; (void)n_in; (void)out_size;
  const float* pred_cls  = (const float*)d_in[0];
  const float* pred_reg  = (const float*)d_in[1];
  const float* anchors   = (const float*)d_in[2];
  const float* strides   = (const float*)d_in[3];
  const float* gt_boxes  = (const float*)d_in[4];
  const int*   gt_labels = (const int*)d_in[5];
  float* out = (float*)d_out;

  char* ws = (char*)d_ws;
  const size_t part_bytes = (size_t)B_ * M_ * CH_ * 8;   // 819200
  const size_t sp_off = part_bytes;                      // 8*128*4 = 4096
  const size_t sw_off = sp_off + 4096;
  const size_t need   = sw_off + 4096;

  if (ws_size >= need) {
    ull*   part    = (ull*)ws;
    float* sp_part = (float*)(ws + sp_off);
    float* sw_part = (float*)(ws + sw_off);
    // 2 graph nodes, zero memsets, zero atomics on the main path
    k_main<<<dim3(CH_, B_), dim3(256), 0, stream>>>(pred_cls, anchors, gt_boxes,
                                                    sp_part, sw_part, part);
    k_finalall<<<dim3(1), dim3(1024), 0, stream>>>(pred_cls, pred_reg, anchors,
                                                   strides, gt_boxes, gt_labels,
                                                   part, sp_part, sw_part, out);
  } else {
    // R6-proven fallback (needs ~7 KB)
    double* sp_sum  = (double*)(ws);
    double* swb_sum = (double*)(ws + 64);
    ull* amin = (ull*)(ws + 128);
    float* lc = (float*)(ws + 128 + 6400);
    float* lb = (float*)(ws + 128 + 6400 + 32);
    hipMemsetAsync(ws, 0, 128, stream);
    hipMemsetAsync(ws + 128, 0xFF, 6400, stream);
    k_passA<<<dim3(N_ / 1024, B_), dim3(256), 0, stream>>>(pred_cls, anchors, gt_boxes,
                                                           sp_sum, swb_sum);
    k_argmin<<<dim3(SEG_, B_ * M_), dim3(256), 0, stream>>>(anchors, gt_boxes, amin);
    k_final_img<<<dim3(B_), dim3(128), 0, stream>>>(pred_cls, pred_reg, anchors,
                                                    strides, gt_boxes, gt_labels,
                                                    amin, sp_sum, swb_sum, lc, lb);
    k_total<<<dim3(1), dim3(64), 0, stream>>>(lc, lb, out);
  }
}

// Round 10
// 225.596 us; speedup vs baseline: 1.1569x; 1.1569x over previous
//
#include <hip/hip_runtime.h>

#define B_ 8
#define N_ 262144
#define M_ 100
#define C_ 7
#define EPSF 1e-7f
#define AB_ 2048                 // anchors per sp_sw block
#define CH_ (N_ / AB_)           // 128 chunks
#define GXC 64                   // grid cells per dim (cell = 16 units)
#define CELLW 16.0f
#define INV_CELL 0.0625f
#define NCELL (GXC * GXC)
// fallback path (R6-proven) params
#define SEG_ 4
#define SEGN_ (N_ / SEG_)

typedef unsigned long long ull;
typedef unsigned int u32;

__device__ __forceinline__ float softplus0(float x) {
  // jnp.logaddexp(0, x) = max(x,0) + log1p(exp(-|x|))
  return fmaxf(x, 0.0f) + log1pf(expf(-fabsf(x)));
}

__device__ __forceinline__ ull u64min(ull a, ull b) { return b < a ? b : a; }

__device__ __forceinline__ int cell_of(float2 a) {
  int ix = (int)(a.x * INV_CELL); ix = ix < 0 ? 0 : (ix > GXC - 1 ? GXC - 1 : ix);
  int iy = (int)(a.y * INV_CELL); iy = iy < 0 ? 0 : (iy > GXC - 1 ? GXC - 1 : iy);
  return iy * GXC + ix;
}

// exact reference d2 sequence (bit-identical to R0's absmax-0.0 kernel)
__device__ __forceinline__ float d2_exact(float gx, float gy, float t1, float2 a) {
  float t2  = __fadd_rn(__fmul_rn(a.x, a.x), __fmul_rn(a.y, a.y));
  float dot = __fmaf_rn(gy, a.y, __fmul_rn(gx, a.x));
  return __fsub_rn(__fadd_rn(t1, t2), __fadd_rn(dot, dot));
}

// ---------------- grid build: count -> scan -> scatter ----------------
__global__ void __launch_bounds__(256)
k_count(const float* __restrict__ anchors, u32* __restrict__ hist) {
  const int n = blockIdx.x * 256 + threadIdx.x;
  float2 a = reinterpret_cast<const float2*>(anchors)[n];
  atomicAdd(&hist[cell_of(a)], 1u);
}

__global__ void __launch_bounds__(1024)
k_scan(u32* __restrict__ hist /*in: counts, out: cursors*/,
       u32* __restrict__ cellStart) {
  __shared__ u32 sA[1024];
  const int t = threadIdx.x;
  u32 h0 = hist[4 * t], h1 = hist[4 * t + 1], h2 = hist[4 * t + 2], h3 = hist[4 * t + 3];
  u32 s = h0 + h1 + h2 + h3;
  sA[t] = s;
  __syncthreads();
  for (int off = 1; off < 1024; off <<= 1) {
    u32 add = (t >= off) ? sA[t - off] : 0u;
    __syncthreads();
    sA[t] += add;
    __syncthreads();
  }
  u32 excl = sA[t] - s;
  u32 e0 = excl, e1 = e0 + h0, e2 = e1 + h1, e3 = e2 + h2;
  cellStart[4 * t] = e0; cellStart[4 * t + 1] = e1;
  cellStart[4 * t + 2] = e2; cellStart[4 * t + 3] = e3;
  hist[4 * t] = e0; hist[4 * t + 1] = e1;       // cursors for scatter
  hist[4 * t + 2] = e2; hist[4 * t + 3] = e3;
  if (t == 1023) cellStart[NCELL] = sA[1023];
}

__global__ void __launch_bounds__(256)
k_scatter(const float* __restrict__ anchors, u32* __restrict__ cur,
          u32* __restrict__ aidx) {
  const int n = blockIdx.x * 256 + threadIdx.x;
  float2 a = reinterpret_cast<const float2*>(anchors)[n];
  u32 pos = atomicAdd(&cur[cell_of(a)], 1u);
  aidx[pos] = (u32)n;
}

// ---------------- k_assign: per (b,m) radius-mark + exact argmin ----------------
// One wave per (b,m). Phase 1: mark map[b][n]=1 for anchors with d2<=9 (cell
// window radius 3.5 is a superset; exact formula decides). Phase 2: expanding
// ring candidate search; all candidates evaluated with the exact clipped-d2
// u64 pack -> identical selection to the reference argmin.
__global__ void __launch_bounds__(64)
k_assign(const float* __restrict__ anchors,
         const float* __restrict__ gt_boxes,
         const u32* __restrict__ cellStart,
         const u32* __restrict__ aidx,
         unsigned char* __restrict__ map,
         ull* __restrict__ amin) {
  const int m = blockIdx.x, b = blockIdx.y;
  const int lane = threadIdx.x;
  const float4 g = reinterpret_cast<const float4*>(gt_boxes)[b * M_ + m];
  const float gx = __fmul_rn(__fadd_rn(g.x, g.z), 0.5f);
  const float gy = __fmul_rn(__fadd_rn(g.y, g.w), 0.5f);
  const float t1 = __fadd_rn(__fmul_rn(gx, gx), __fmul_rn(gy, gy));
  const float2* an = reinterpret_cast<const float2*>(anchors);
  unsigned char* mp = map + (size_t)b * N_;

  // ---- phase 1: radius-3.5 ball -> mark d2<=9 anchors
  {
    int x0 = (int)floorf((gx - 3.5f) * INV_CELL); x0 = x0 < 0 ? 0 : (x0 > GXC - 1 ? GXC - 1 : x0);
    int x1 = (int)floorf((gx + 3.5f) * INV_CELL); x1 = x1 < 0 ? 0 : (x1 > GXC - 1 ? GXC - 1 : x1);
    int y0 = (int)floorf((gy - 3.5f) * INV_CELL); y0 = y0 < 0 ? 0 : (y0 > GXC - 1 ? GXC - 1 : y0);
    int y1 = (int)floorf((gy + 3.5f) * INV_CELL); y1 = y1 < 0 ? 0 : (y1 > GXC - 1 ? GXC - 1 : y1);
    for (int cy = y0; cy <= y1; ++cy)
      for (int cx = x0; cx <= x1; ++cx) {
        u32 s = cellStart[cy * GXC + cx], e = cellStart[cy * GXC + cx + 1];
        for (u32 j = s + lane; j < e; j += 64) {
          u32 n = aidx[j];
          if (d2_exact(gx, gy, t1, an[n]) <= 9.0f) mp[n] = 1;
        }
      }
  }

  // ---- phase 2: argmin with expanding-ring guarantee
  int cx0 = (int)(gx * INV_CELL); cx0 = cx0 < 0 ? 0 : (cx0 > GXC - 1 ? GXC - 1 : cx0);
  int cy0 = (int)(gy * INV_CELL); cy0 = cy0 < 0 ? 0 : (cy0 > GXC - 1 ? GXC - 1 : cy0);
  int bidx[6];
#pragma unroll
  for (int i = 0; i < 6; ++i) bidx[i] = ((lane ^ (1 << i)) << 2);

  ull best = 0xffffffffffffffffULL;
  for (int ring = 1; ring < GXC; ++ring) {
    best = 0xffffffffffffffffULL;
    int x0 = cx0 - ring < 0 ? 0 : cx0 - ring;
    int x1 = cx0 + ring > GXC - 1 ? GXC - 1 : cx0 + ring;
    int y0 = cy0 - ring < 0 ? 0 : cy0 - ring;
    int y1 = cy0 + ring > GXC - 1 ? GXC - 1 : cy0 + ring;
    for (int cy = y0; cy <= y1; ++cy)
      for (int cx = x0; cx <= x1; ++cx) {
        u32 s = cellStart[cy * GXC + cx], e = cellStart[cy * GXC + cx + 1];
        for (u32 j = s + lane; j < e; j += 64) {
          u32 n = aidx[j];
          float d2c = fmaxf(d2_exact(gx, gy, t1, an[n]), 0.0f);  // ref clip
          best = u64min(best, ((ull)__float_as_uint(d2c) << 32) | (ull)n);
        }
      }
#pragma unroll
    for (int i = 0; i < 6; ++i) {
      int lo = __builtin_amdgcn_ds_bpermute(bidx[i], (int)(u32)(best & 0xffffffffULL));
      int hi = __builtin_amdgcn_ds_bpermute(bidx[i], (int)(u32)(best >> 32));
      best = u64min(best, ((ull)(u32)hi << 32) | (ull)(u32)lo);
    }
    // sufficiency: outside window true-d2 >= cov^2; formula err <= ~1.5; margin 4
    float lx = (cx0 - ring < 0)       ? 1e18f : gx - CELLW * (float)(cx0 - ring);
    float hx = (cx0 + ring > GXC - 1) ? 1e18f : CELLW * (float)(cx0 + ring + 1) - gx;
    float ly = (cy0 - ring < 0)       ? 1e18f : gy - CELLW * (float)(cy0 - ring);
    float hy = (cy0 + ring > GXC - 1) ? 1e18f : CELLW * (float)(cy0 + ring + 1) - gy;
    float cov = fminf(fminf(lx, hx), fminf(ly, hy));
    float bf = __uint_as_float((u32)(best >> 32));
    if (bf <= cov * cov - 4.0f) break;
  }
  if (lane == 0) amin[b * M_ + m] = best;
}

// ---------------- k_sp_sw: softplus chunk partials + map->sw chunk partials ----------------
// grid (CH_, B), 256 threads. Identical accumulation order/trees as R9 (absmax 0.0).
__global__ void __launch_bounds__(256)
k_sp_sw(const float* __restrict__ pred_cls,
        const unsigned char* __restrict__ map,
        float* __restrict__ sp_part,
        float* __restrict__ sw_part) {
  const int b = blockIdx.y, c = blockIdx.x, t = threadIdx.x;
  __shared__ float red[256];
  const float4* pc = reinterpret_cast<const float4*>(
      pred_cls + (size_t)b * (size_t)(N_ * C_) + (size_t)c * (AB_ * C_));
  float acc_sp = 0.f;
  for (int k = 0; k < 14; ++k) {
    float4 v = pc[t + k * 256];
    acc_sp += softplus0(v.x) + softplus0(v.y) + softplus0(v.z) + softplus0(v.w);
  }
  red[t] = acc_sp;
  __syncthreads();
  for (int s = 128; s > 0; s >>= 1) {
    if (t < s) red[t] += red[t + s];
    __syncthreads();
  }
  if (t == 0) sp_part[b * CH_ + c] = red[0];

  const unsigned char* mp = map + (size_t)b * N_ + (size_t)c * AB_;
  float accw = 0.f;
#pragma unroll
  for (int k = 0; k < 8; ++k) accw += mp[t + k * 256] ? 0.1f : 1.0f;
  __syncthreads();
  red[t] = accw;
  __syncthreads();
  for (int s = 128; s > 0; s >>= 1) {
    if (t < s) red[t] += red[t + s];
    __syncthreads();
  }
  if (t == 0) sw_part[b * CH_ + c] = red[0];
}

// ---------------- k_final3: per-image losses (amin direct, corr from map) ----------------
__global__ void __launch_bounds__(128)
k_final3(const float* __restrict__ pred_cls,
         const float* __restrict__ pred_reg,
         const float* __restrict__ anchors,
         const float* __restrict__ strides,
         const float* __restrict__ gt_boxes,
         const int* __restrict__ gt_labels,
         const ull* __restrict__ amin,
         const unsigned char* __restrict__ map,
         const float* __restrict__ sp_part,
         const float* __restrict__ sw_part,
         float* __restrict__ lc, float* __restrict__ lb) {
  const int b = blockIdx.x;
  const int t = threadIdx.x;  // 128
  __shared__ unsigned asg[M_];
  __shared__ int cid[M_];
  __shared__ unsigned srt[M_];
  __shared__ float red[128];
  __shared__ double redd[128];
  __shared__ int dupCount;
  __shared__ double spT, swT;
  if (t == 0) dupCount = 0;
  if (t < M_) {
    asg[t] = (unsigned)(amin[b * M_ + t] & 0xffffffffULL);
    int cc = gt_labels[b * M_ + t] - 1;
    cc = cc < 0 ? 0 : (cc > C_ - 1 ? C_ - 1 : cc);
    cid[t] = cc;
  }
  // f64 reduce of the 128 chunk partials (same tree as R9-verified)
  redd[t] = (double)sp_part[b * CH_ + t];
  __syncthreads();
  for (int s = 64; s > 0; s >>= 1) {
    if (t < s) redd[t] += redd[t + s];
    __syncthreads();
  }
  if (t == 0) spT = redd[0];
  __syncthreads();
  redd[t] = (double)sw_part[b * CH_ + t];
  __syncthreads();
  for (int s = 64; s > 0; s >>= 1) {
    if (t < s) redd[t] += redd[t + s];
    __syncthreads();
  }
  if (t == 0) swT = redd[0];
  __syncthreads();

  // tgt sum with (anchor,cls)-pair dedup; anchor-dup detection; pos-correction
  // for each DISTINCT assigned anchor: its neg-weight read straight from map.
  float tg = 0.f, corr = 0.f;
  if (t < M_) {
    bool dupPair = false, dupIdx = false;
    for (int m = 0; m < t; ++m) {
      if (asg[m] == asg[t]) {
        dupIdx = true;
        if (cid[m] == cid[t]) dupPair = true;
      }
    }
    if (!dupPair) tg = pred_cls[((size_t)b * N_ + asg[t]) * C_ + cid[t]];
    if (dupIdx) atomicAdd(&dupCount, 1);
    if (!dupIdx) corr = map[(size_t)b * N_ + asg[t]] ? 0.1f : 1.0f;
  }
  red[t] = tg;
  __syncthreads();
  for (int s = 64; s > 0; s >>= 1) {
    if (t < s) red[t] += red[t + s];
    __syncthreads();
  }
  const float tgt_total = red[0];
  __syncthreads();
  red[t] = corr;
  __syncthreads();
  for (int s = 64; s > 0; s >>= 1) {
    if (t < s) red[t] += red[t + s];
    __syncthreads();
  }
  const float corr_total = red[0];
  const bool uniqueAll = (dupCount == 0);
  __syncthreads();

  if (uniqueAll && t < M_) {
    const unsigned v = asg[t];
    int rank = 0;
    for (int m = 0; m < M_; ++m) rank += (asg[m] < v) ? 1 : 0;
    srt[rank] = v;
  }
  __syncthreads();

  float gl = 0.f;
  if (t < M_) {
    const unsigned q = uniqueAll ? srt[t] : asg[t];
    float4 r = reinterpret_cast<const float4*>(pred_reg)[(size_t)b * N_ + q];
    float2 a = reinterpret_cast<const float2*>(anchors)[q];
    float s = strides[q];
    float cx = a.x + r.x * s, cy = a.y + r.y * s;
    float hx = (expf(r.z) * s) * 0.5f, hy = (expf(r.w) * s) * 0.5f;
    float px0 = cx - hx, py0 = cy - hy, px1 = cx + hx, py1 = cy + hy;
    float4 g = reinterpret_cast<const float4*>(gt_boxes)[b * M_ + t];
    float ap = (px1 - px0) * (py1 - py0);
    float ag = (g.z - g.x) * (g.w - g.y);
    float ltx = fmaxf(px0, g.x), lty = fmaxf(py0, g.y);
    float rbx = fminf(px1, g.z), rby = fminf(py1, g.w);
    float wix = fmaxf(rbx - ltx, 0.f), wiy = fmaxf(rby - lty, 0.f);
    float inter = wix * wiy;
    float uni = ap + ag - inter;
    float iou = inter / (uni + EPSF);
    float lcx = fminf(px0, g.x), lcy = fminf(py0, g.y);
    float rcx = fmaxf(px1, g.z), rcy = fmaxf(py1, g.w);
    float wcx = fmaxf(rcx - lcx, 0.f), wcy = fmaxf(rcy - lcy, 0.f);
    float ac = wcx * wcy;
    float giou = iou - (ac - uni) / (ac + EPSF);
    gl = 1.f - giou;
  }
  __syncthreads();
  red[t] = gl;
  __syncthreads();
  for (int s = 64; s > 0; s >>= 1) {
    if (t < s) red[t] += red[t + s];
    __syncthreads();
  }
  if (t == 0) {
    lb[b] = red[0] / (float)M_;
    float bce = (float)((spT - (double)tgt_total) / (double)(N_ * C_));
    float swm = (float)((swT + (double)corr_total) / (double)N_);
    lc[b] = bce * swm;
  }
}

// ---------------- scalar combine ----------------
__global__ void __launch_bounds__(64)
k_total(const float* __restrict__ lc, const float* __restrict__ lb,
        float* __restrict__ out) {
  if (threadIdx.x == 0 && blockIdx.x == 0) {
    float sc = 0.f, sb = 0.f;
    for (int b = 0; b < B_; ++b) { sc += lc[b]; sb += lb[b]; }
    out[0] = sc / 8.0f + 2.0f * (sb / 8.0f);
  }
}

// ---------------- fallback (R6-proven) kernels, used if ws_size is small ----------------
__global__ void __launch_bounds__(256)
k_passA(const float* __restrict__ pred_cls,
        const float* __restrict__ anchors,
        const float* __restrict__ gt_boxes,
        double* __restrict__ sp_sum,
        double* __restrict__ swb_sum) {
  const int b = blockIdx.y;
  const int c = blockIdx.x;
  const int t = threadIdx.x;
  __shared__ float4 gt4[M_];
  __shared__ float red[256];
  if (t < M_) {
    float4 g = reinterpret_cast<const float4*>(gt_boxes)[b * M_ + t];
    float gx = __fmul_rn(__fadd_rn(g.x, g.z), 0.5f);
    float gy = __fmul_rn(__fadd_rn(g.y, g.w), 0.5f);
    gt4[t] = make_float4(gx, gy, __fadd_rn(__fmul_rn(gx, gx), __fmul_rn(gy, gy)), 0.f);
  }
  const float4* pc = reinterpret_cast<const float4*>(
      pred_cls + (size_t)b * (size_t)(N_ * C_) + (size_t)c * (1024 * C_));
  float acc_sp = 0.f;
#pragma unroll
  for (int k = 0; k < 7; ++k) {
    float4 v = pc[t + k * 256];
    acc_sp += softplus0(v.x) + softplus0(v.y) + softplus0(v.z) + softplus0(v.w);
  }
  red[t] = acc_sp;
  __syncthreads();
  for (int s = 128; s > 0; s >>= 1) {
    if (t < s) red[t] += red[t + s];
    __syncthreads();
  }
  if (t == 0) atomicAdd(&sp_sum[b], (double)red[0]);
  const int n0 = c * 1024;
  float ax[4], ay[4], t2[4], mind[4];
#pragma unroll
  for (int k = 0; k < 4; ++k) {
    float2 a = reinterpret_cast<const float2*>(anchors)[n0 + t + k * 256];
    ax[k] = a.x; ay[k] = a.y;
    t2[k] = __fadd_rn(__fmul_rn(a.x, a.x), __fmul_rn(a.y, a.y));
    mind[k] = __int_as_float(0x7f800000);
  }
#pragma unroll 2
  for (int m = 0; m < M_; ++m) {
    const float4 g = gt4[m];
#pragma unroll
    for (int k = 0; k < 4; ++k) {
      float dot = __fmaf_rn(g.y, ay[k], __fmul_rn(g.x, ax[k]));
      float d2  = __fsub_rn(__fadd_rn(g.z, t2[k]), __fadd_rn(dot, dot));
      mind[k] = fminf(mind[k], fmaxf(d2, 0.0f));
    }
  }
  float accw = 0.f;
#pragma unroll
  for (int k = 0; k < 4; ++k) accw += (sqrtf(mind[k]) > 3.0f) ? 1.0f : 0.1f;
  __syncthreads();
  red[t] = accw;
  __syncthreads();
  for (int s = 128; s > 0; s >>= 1) {
    if (t < s) red[t] += red[t + s];
    __syncthreads();
  }
  if (t == 0) atomicAdd(&swb_sum[b], (double)red[0]);
}

__global__ void __launch_bounds__(256)
k_argmin(const float* __restrict__ anchors,
         const float* __restrict__ gt_boxes,
         ull* __restrict__ amin) {
  const int bm  = blockIdx.y;
  const int seg = blockIdx.x;
  const float4 g = reinterpret_cast<const float4*>(gt_boxes)[bm];
  const float gx = __fmul_rn(__fadd_rn(g.x, g.z), 0.5f);
  const float gy = __fmul_rn(__fadd_rn(g.y, g.w), 0.5f);
  const float t1 = __fadd_rn(__fmul_rn(gx, gx), __fmul_rn(gy, gy));
  const float2* an = reinterpret_cast<const float2*>(anchors);
  float best = __int_as_float(0x7f800000);
  unsigned bestn = 0;
  const int n0 = seg * SEGN_;
#pragma unroll 4
  for (int n = n0 + threadIdx.x; n < n0 + SEGN_; n += 256) {
    float2 a = an[n];
    float d2 = d2_exact(gx, gy, t1, a);
    d2 = fmaxf(d2, 0.0f);
    if (d2 < best) { best = d2; bestn = (unsigned)n; }
  }
  ull pk = ((ull)__float_as_uint(best) << 32) | (ull)bestn;
  __shared__ ull red[256];
  const int t = threadIdx.x;
  red[t] = pk;
  __syncthreads();
  for (int s = 128; s > 0; s >>= 1) {
    if (t < s) {
      ull o = red[t + s];
      if (o < red[t]) red[t] = o;
    }
    __syncthreads();
  }
  if (t == 0) atomicMin(&amin[bm], red[0]);
}

__global__ void __launch_bounds__(128)
k_final_img(const float* __restrict__ pred_cls,
            const float* __restrict__ pred_reg,
            const float* __restrict__ anchors,
            const float* __restrict__ strides,
            const float* __restrict__ gt_boxes,
            const int* __restrict__ gt_labels,
            const ull* __restrict__ amin,
            const double* __restrict__ sp_sum,
            const double* __restrict__ swb_sum,
            float* __restrict__ lc, float* __restrict__ lb) {
  const int b = blockIdx.x;
  const int t = threadIdx.x;
  __shared__ unsigned asg[M_];
  __shared__ int cid[M_];
  __shared__ unsigned srt[M_];
  __shared__ float4 gt4[M_];
  __shared__ float red[128];
  __shared__ int dupCount;
  if (t == 0) dupCount = 0;
  if (t < M_) {
    asg[t] = (unsigned)(amin[b * M_ + t] & 0xffffffffULL);
    int c = gt_labels[b * M_ + t] - 1;
    c = c < 0 ? 0 : (c > C_ - 1 ? C_ - 1 : c);
    cid[t] = c;
    float4 g = reinterpret_cast<const float4*>(gt_boxes)[b * M_ + t];
    float gx = __fmul_rn(__fadd_rn(g.x, g.z), 0.5f);
    float gy = __fmul_rn(__fadd_rn(g.y, g.w), 0.5f);
    gt4[t] = make_float4(gx, gy, __fadd_rn(__fmul_rn(gx, gx), __fmul_rn(gy, gy)), 0.f);
  }
  __syncthreads();
  float tg = 0.f, corr = 0.f;
  if (t < M_) {
    bool dupPair = false, dupIdx = false;
    for (int m = 0; m < t; ++m) {
      if (asg[m] == asg[t]) {
        dupIdx = true;
        if (cid[m] == cid[t]) dupPair = true;
      }
    }
    if (!dupPair) tg = pred_cls[((size_t)b * N_ + asg[t]) * C_ + cid[t]];
    if (dupIdx) atomicAdd(&dupCount, 1);
    if (!dupIdx) {
      float2 a = reinterpret_cast<const float2*>(anchors)[asg[t]];
      float t2 = __fadd_rn(__fmul_rn(a.x, a.x), __fmul_rn(a.y, a.y));
      float mind = __int_as_float(0x7f800000);
      for (int m = 0; m < M_; ++m) {
        float4 g = gt4[m];
        float dot = __fmaf_rn(g.y, a.y, __fmul_rn(g.x, a.x));
        float d2  = __fsub_rn(__fadd_rn(g.z, t2), __fadd_rn(dot, dot));
        mind = fminf(mind, fmaxf(d2, 0.0f));
      }
      corr = (sqrtf(mind) > 3.0f) ? 1.0f : 0.1f;
    }
  }
  red[t] = tg;
  __syncthreads();
  for (int s = 64; s > 0; s >>= 1) {
    if (t < s) red[t] += red[t + s];
    __syncthreads();
  }
  const float tgt_total = red[0];
  __syncthreads();
  red[t] = corr;
  __syncthreads();
  for (int s = 64; s > 0; s >>= 1) {
    if (t < s) red[t] += red[t + s];
    __syncthreads();
  }
  const float corr_total = red[0];
  const bool uniqueAll = (dupCount == 0);
  __syncthreads();
  if (uniqueAll && t < M_) {
    const unsigned v = asg[t];
    int rank = 0;
    for (int m = 0; m < M_; ++m) rank += (asg[m] < v) ? 1 : 0;
    srt[rank] = v;
  }
  __syncthreads();
  float gl = 0.f;
  if (t < M_) {
    const unsigned q = uniqueAll ? srt[t] : asg[t];
    float4 r = reinterpret_cast<const float4*>(pred_reg)[(size_t)b * N_ + q];
    float2 a = reinterpret_cast<const float2*>(anchors)[q];
    float s = strides[q];
    float cx = a.x + r.x * s, cy = a.y + r.y * s;
    float hx = (expf(r.z) * s) * 0.5f, hy = (expf(r.w) * s) * 0.5f;
    float px0 = cx - hx, py0 = cy - hy, px1 = cx + hx, py1 = cy + hy;
    float4 g = reinterpret_cast<const float4*>(gt_boxes)[b * M_ + t];
    float ap = (px1 - px0) * (py1 - py0);
    float ag = (g.z - g.x) * (g.w - g.y);
    float ltx = fmaxf(px0, g.x), lty = fmaxf(py0, g.y);
    float rbx = fminf(px1, g.z), rby = fminf(py1, g.w);
    float wix = fmaxf(rbx - ltx, 0.f), wiy = fmaxf(rby - lty, 0.f);
    float inter = wix * wiy;
    float uni = ap + ag - inter;
    float iou = inter / (uni + EPSF);
    float lcx = fminf(px0, g.x), lcy = fminf(py0, g.y);
    float rcx = fmaxf(px1, g.z), rcy = fmaxf(py1, g.w);
    float wcx = fmaxf(rcx - lcx, 0.f), wcy = fmaxf(rcy - lcy, 0.f);
    float ac = wcx * wcy;
    float giou = iou - (ac - uni) / (ac + EPSF);
    gl = 1.f - giou;
  }
  __syncthreads();
  red[t] = gl;
  __syncthreads();
  for (int s = 64; s > 0; s >>= 1) {
    if (t < s) red[t] += red[t + s];
    __syncthreads();
  }
  if (t == 0) {
    lb[b] = red[0] / (float)M_;
    float bce = (float)((sp_sum[b] - (double)tgt_total) / (double)(N_ * C_));
    float swm = (float)((swb_sum[b] + (double)corr_total) / (double)N_);
    lc[b] = bce * swm;
  }
}

// ---------------- launch ----------------
extern "C" void kernel_launch(void* const* d_in, const int* in_sizes, int n_in,
                              void* d_out, int out_size, void* d_ws, size_t ws_size,
                              hipStream_t stream) {
  (void)in_sizes; (void)n_in; (void)out_size;
  const float* pred_cls  = (const float*)d_in[0];
  const float* pred_reg  = (const float*)d_in[1];
  const float* anchors   = (const float*)d_in[2];
  const float* strides   = (const float*)d_in[3];
  const float* gt_boxes  = (const float*)d_in[4];
  const int*   gt_labels = (const int*)d_in[5];
  float* out = (float*)d_out;

  char* ws = (char*)d_ws;
  const size_t off_cs   = 0;                         // cellStart: 4097 u32
  const size_t off_cur  = 16512;                     // hist/cursor: 4096 u32
  const size_t off_aidx = off_cur + 16384;           // 262144 u32 = 1 MB
  const size_t off_map  = off_aidx + 1048576;        // 8*N bytes = 2 MB
  const size_t off_sp   = off_map + (size_t)B_ * N_; // 128*8 f32
  const size_t off_sw   = off_sp + 4096;
  const size_t off_amin = off_sw + 4096;             // 800 u64
  const size_t off_lc   = off_amin + 6400;
  const size_t off_lb   = off_lc + 64;
  const size_t need     = off_lb + 64;

  if (ws_size >= need) {
    u32* cellStart = (u32*)(ws + off_cs);
    u32* cur       = (u32*)(ws + off_cur);
    u32* aidx      = (u32*)(ws + off_aidx);
    unsigned char* map = (unsigned char*)(ws + off_map);
    float* sp_part = (float*)(ws + off_sp);
    float* sw_part = (float*)(ws + off_sw);
    ull*   amin    = (ull*)(ws + off_amin);
    float* lc      = (float*)(ws + off_lc);
    float* lb      = (float*)(ws + off_lb);

    hipMemsetAsync(cur, 0, 16384, stream);
    hipMemsetAsync(map, 0, (size_t)B_ * N_, stream);
    k_count<<<dim3(N_ / 256), dim3(256), 0, stream>>>(anchors, cur);
    k_scan<<<dim3(1), dim3(1024), 0, stream>>>(cur, cellStart);
    k_scatter<<<dim3(N_ / 256), dim3(256), 0, stream>>>(anchors, cur, aidx);
    k_assign<<<dim3(M_, B_), dim3(64), 0, stream>>>(anchors, gt_boxes, cellStart,
                                                    aidx, map, amin);
    k_sp_sw<<<dim3(CH_, B_), dim3(256), 0, stream>>>(pred_cls, map, sp_part, sw_part);
    k_final3<<<dim3(B_), dim3(128), 0, stream>>>(pred_cls, pred_reg, anchors, strides,
                                                 gt_boxes, gt_labels, amin, map,
                                                 sp_part, sw_part, lc, lb);
    k_total<<<dim3(1), dim3(64), 0, stream>>>(lc, lb, out);
  } else {
    // R6-proven fallback (needs ~7 KB)
    double* sp_sum  = (double*)(ws);
    double* swb_sum = (double*)(ws + 64);
    ull* amin = (ull*)(ws + 128);
    float* lc = (float*)(ws + 128 + 6400);
    float* lb = (float*)(ws + 128 + 6400 + 32);
    hipMemsetAsync(ws, 0, 128, stream);
    hipMemsetAsync(ws + 128, 0xFF, 6400, stream);
    k_passA<<<dim3(N_ / 1024, B_), dim3(256), 0, stream>>>(pred_cls, anchors, gt_boxes,
                                                           sp_sum, swb_sum);
    k_argmin<<<dim3(SEG_, B_ * M_), dim3(256), 0, stream>>>(anchors, gt_boxes, amin);
    k_final_img<<<dim3(B_), dim3(128), 0, stream>>>(pred_cls, pred_reg, anchors,
                                                    strides, gt_boxes, gt_labels,
                                                    amin, sp_sum, swb_sum, lc, lb);
    k_total<<<dim3(1), dim3(64), 0, stream>>>(lc, lb, out);
  }
}